// Round 6
// baseline (615.103 us; speedup 1.0000x reference)
//
#include <hip/hip_runtime.h>
#include <math.h>

#define HEADS 8
#define DK 64
#define DMODEL 512
#define BATCH 2
#define SEQ 2048
#define BH (BATCH * HEADS)

using f32x4 = __attribute__((ext_vector_type(4))) float;
using s16x8 = __attribute__((ext_vector_type(8))) short;
using f16x4 = __attribute__((ext_vector_type(4))) _Float16;

union FragU {
  uint4 u;
  s16x8 s;
  unsigned short us[8];
};
union F16U {
  uint2 u;
  f16x4 h;
  _Float16 e[4];
};

__device__ __forceinline__ unsigned short f32_to_bf16(float f) {
  unsigned int u = __float_as_uint(f);
  u += 0x7fffu + ((u >> 16) & 1u);
  return (unsigned short)(u >> 16);
}
__device__ __forceinline__ float bf16_to_f32(unsigned short h) {
  return __uint_as_float(((unsigned int)h) << 16);
}

// Shared split-bf16 S-tile: S[q=lr][k=k0+lg*4+r] via swapped-operand MFMA.
// A = K rows (m=kseq), B = Q rows (n=q). Order fixed -> stats & pv agree
// bit-identically, so exp(s - m) <= 1 is guaranteed.
__device__ __forceinline__ f32x4 s_tile(const FragU& kh0, const FragU& kl0,
                                        const FragU& kh1, const FragU& kl1,
                                        const FragU& qh0, const FragU& ql0,
                                        const FragU& qh1, const FragU& ql1) {
  f32x4 s = {};
  s = __builtin_amdgcn_mfma_f32_16x16x32_bf16(kh0.s, qh0.s, s, 0, 0, 0);
  s = __builtin_amdgcn_mfma_f32_16x16x32_bf16(kh0.s, ql0.s, s, 0, 0, 0);
  s = __builtin_amdgcn_mfma_f32_16x16x32_bf16(kl0.s, qh0.s, s, 0, 0, 0);
  s = __builtin_amdgcn_mfma_f32_16x16x32_bf16(kh1.s, qh1.s, s, 0, 0, 0);
  s = __builtin_amdgcn_mfma_f32_16x16x32_bf16(kh1.s, ql1.s, s, 0, 0, 0);
  s = __builtin_amdgcn_mfma_f32_16x16x32_bf16(kl1.s, qh1.s, s, 0, 0, 0);
  return s;
}

// ---------------------------------------------------------------------------
// mask int32 [B][S][S] -> packed bits [B][S][S/32]. One block per row.
// ---------------------------------------------------------------------------
__global__ __launch_bounds__(256) void pack_mask_kernel(
    const int* __restrict__ mask, unsigned int* __restrict__ bits) {
  const size_t row = blockIdx.x;  // B*S = 4096 rows
  const int wv = threadIdx.x >> 6, lane = threadIdx.x & 63;
  #pragma unroll
  for (int i = 0; i < 8; ++i) {
    const int c = wv * 512 + i * 64 + lane;
    unsigned long long bal = __ballot(mask[row * SEQ + c] != 0);
    if (lane == 0) {
      bits[row * 64 + (c >> 5)] = (unsigned int)bal;
      bits[row * 64 + (c >> 5) + 1] = (unsigned int)(bal >> 32);
    }
  }
}

// ---------------------------------------------------------------------------
// W[512][512] f32 -> Wt hi/lo bf16 in [n][k] (transposed) layout.
// ---------------------------------------------------------------------------
__global__ __launch_bounds__(256) void wsplit_kernel(
    const float* __restrict__ W, unsigned short* __restrict__ WtHi,
    unsigned short* __restrict__ WtLo) {
  __shared__ float t[64][65];
  const int k0 = blockIdx.x * 64, n0 = blockIdx.y * 64;
  const int tid = threadIdx.x;
  const int r = tid >> 2, c = (tid & 3) * 16;
  #pragma unroll
  for (int e = 0; e < 4; ++e) {
    f32x4 v = *(const f32x4*)&W[(size_t)(k0 + r) * DMODEL + n0 + c + e * 4];
    #pragma unroll
    for (int j = 0; j < 4; ++j) t[r][c + e * 4 + j] = v[j];
  }
  __syncthreads();
  const int rn = tid >> 2, ck = (tid & 3) * 16;
  #pragma unroll
  for (int half = 0; half < 2; ++half) {
    FragU hi, lo;
    #pragma unroll
    for (int e = 0; e < 8; ++e) {
      float x = t[ck + half * 8 + e][rn];
      unsigned short h = f32_to_bf16(x);
      hi.us[e] = h;
      lo.us[e] = f32_to_bf16(x - bf16_to_f32(h));
    }
    const size_t o = (size_t)(n0 + rn) * DMODEL + k0 + ck + half * 8;
    *(uint4*)&WtHi[o] = hi.u;
    *(uint4*)&WtLo[o] = lo.u;
  }
}

// ---------------------------------------------------------------------------
// MFMA projection GEMM. Tile 64x32 per block (wave = 16q x 32n), grid (64,16)
// -> 4096 waves = 16/CU for latency hiding.
// MODE 1: Y -> head-split bf16 hi/lo pair [BH][S][DK]
// MODE 2: Y -> head-split f16             [BH][S][DK]   (V path)
// MODE 3: X is bf16 (ctx), Y -> flat f32  [M][512]
// ---------------------------------------------------------------------------
template <int MODE>
__global__ __launch_bounds__(256) void proj_mfma_kernel(
    const float* __restrict__ X, const unsigned short* __restrict__ X16,
    const unsigned short* __restrict__ WtHi,
    const unsigned short* __restrict__ WtLo, const float* __restrict__ bias,
    float* __restrict__ Yf, unsigned short* __restrict__ Yhi,
    unsigned short* __restrict__ Ylo) {
  const int tid = threadIdx.x, wv = tid >> 6, lane = tid & 63;
  const int lr = lane & 15, lg = lane >> 4;
  const int m0 = blockIdx.x * 64 + wv * 16;
  const int n0 = blockIdx.y * 32;

  f32x4 acc[2] = {};
  #pragma unroll 2
  for (int k0 = 0; k0 < 512; k0 += 64) {
    FragU ah[2], al[2];
    #pragma unroll
    for (int dc = 0; dc < 2; ++dc) {
      const size_t xi = (size_t)(m0 + lr) * DMODEL + k0 + dc * 32 + lg * 8;
      if (MODE == 3) {
        ah[dc].u = *(const uint4*)&X16[xi];
      } else {
        f32x4 x0 = *(const f32x4*)&X[xi];
        f32x4 x1 = *(const f32x4*)&X[xi + 4];
        #pragma unroll
        for (int t = 0; t < 4; ++t) {
          unsigned short h0 = f32_to_bf16(x0[t]);
          unsigned short h1 = f32_to_bf16(x1[t]);
          ah[dc].us[t] = h0;
          ah[dc].us[4 + t] = h1;
          al[dc].us[t] = f32_to_bf16(x0[t] - bf16_to_f32(h0));
          al[dc].us[4 + t] = f32_to_bf16(x1[t] - bf16_to_f32(h1));
        }
      }
    }
    #pragma unroll
    for (int jt = 0; jt < 2; ++jt) {
      #pragma unroll
      for (int dc = 0; dc < 2; ++dc) {
        const size_t wi =
            (size_t)(n0 + jt * 16 + lr) * DMODEL + k0 + dc * 32 + lg * 8;
        FragU bh, bl;
        bh.u = *(const uint4*)&WtHi[wi];
        bl.u = *(const uint4*)&WtLo[wi];
        acc[jt] = __builtin_amdgcn_mfma_f32_16x16x32_bf16(ah[dc].s, bh.s, acc[jt], 0, 0, 0);
        acc[jt] = __builtin_amdgcn_mfma_f32_16x16x32_bf16(ah[dc].s, bl.s, acc[jt], 0, 0, 0);
        if (MODE != 3)
          acc[jt] = __builtin_amdgcn_mfma_f32_16x16x32_bf16(al[dc].s, bh.s, acc[jt], 0, 0, 0);
      }
    }
  }

  #pragma unroll
  for (int jt = 0; jt < 2; ++jt) {
    const int n = n0 + jt * 16 + lr;
    const float bi = bias[n];
    #pragma unroll
    for (int r = 0; r < 4; ++r) {
      const int m = m0 + lg * 4 + r;
      const float v = acc[jt][r] + bi;
      if (MODE == 3) {
        Yf[(size_t)m * DMODEL + n] = v;
      } else {
        const int b = m >> 11, s = m & 2047;
        const int h = n >> 6, d = n & 63;
        const size_t idx = (((size_t)(b * HEADS + h) * SEQ) + s) * DK + d;
        if (MODE == 2) {
          union { _Float16 hh; unsigned short uu; } cv;
          cv.hh = (_Float16)v;
          Yhi[idx] = cv.uu;
        } else {
          unsigned short hi = f32_to_bf16(v);
          Yhi[idx] = hi;
          Ylo[idx] = f32_to_bf16(v - bf16_to_f32(hi));
        }
      }
    }
  }
}

// ---------------------------------------------------------------------------
// Vh[bh][s][d] u16 -> Vt[bh][d][s] u16 (format-agnostic transpose)
// ---------------------------------------------------------------------------
__global__ __launch_bounds__(256) void vtrans_kernel(
    const unsigned short* __restrict__ Vh, unsigned short* __restrict__ Vt) {
  __shared__ unsigned short t[64][72];
  const int tid = threadIdx.x;
  const int bh = blockIdx.y, s0 = blockIdx.x * 64;
  #pragma unroll
  for (int e = 0; e < 2; ++e) {
    int c = tid + e * 256;
    int r = c >> 3, c8 = (c & 7) * 8;
    *(uint4*)&t[r][c8] = *(const uint4*)&Vh[((size_t)bh * SEQ + s0 + r) * DK + c8];
  }
  __syncthreads();
  const int d = tid >> 2, sc0 = (tid & 3) * 16;
  #pragma unroll
  for (int e = 0; e < 16; ++e)
    Vt[((size_t)bh * DK + d) * SEQ + s0 + sc0 + e] = t[sc0 + e][d];
}

// ---------------------------------------------------------------------------
// K1 v3 (swapped): per-lane online (m,l). Wave = q16 x k512 stripe. No LDS.
// Lane (lg,lr): q = q0w+lr, k = k0+lg*4+r.
// ---------------------------------------------------------------------------
__global__ __launch_bounds__(256) void stats_kernel(
    const unsigned short* __restrict__ Qhi, const unsigned short* __restrict__ Qlo,
    const unsigned short* __restrict__ Khi, const unsigned short* __restrict__ Klo,
    const unsigned int* __restrict__ bits, float* __restrict__ stats_part) {
  const int bh = blockIdx.z, b = bh >> 3;
  const int tid = threadIdx.x, wv = tid >> 6, lane = tid & 63;
  const int lr = lane & 15, lg = lane >> 4;
  const int q0w = blockIdx.x * 64 + wv * 16;
  const int kb = blockIdx.y;

  FragU qh[2], ql[2];
  #pragma unroll
  for (int dc = 0; dc < 2; ++dc) {
    const size_t qi = ((size_t)bh * SEQ + q0w + lr) * DK + dc * 32 + lg * 8;
    qh[dc].u = *(const uint4*)&Qhi[qi];
    ql[dc].u = *(const uint4*)&Qlo[qi];
  }
  const unsigned int* brow = bits + ((size_t)b * SEQ + q0w + lr) * 64 + kb * 16;
  const size_t kbase0 = (size_t)bh * SEQ + kb * 512;

  float mrun = -1e30f, lrun = 0.f;
  for (int kt = 0; kt < 32; ++kt) {
    FragU kh0, kh1, kl0, kl1;
    const size_t krow = (kbase0 + kt * 16 + lr) * DK + lg * 8;
    kh0.u = *(const uint4*)&Khi[krow];
    kh1.u = *(const uint4*)&Khi[krow + 32];
    kl0.u = *(const uint4*)&Klo[krow];
    kl1.u = *(const uint4*)&Klo[krow + 32];
    f32x4 s = s_tile(kh0, kl0, kh1, kl1, qh[0], ql[0], qh[1], ql[1]);

    const unsigned int w = brow[kt >> 1];
    const int bsh = (kt & 1) << 4;
    float vals[4];
    #pragma unroll
    for (int r = 0; r < 4; ++r)
      vals[r] = ((w >> (bsh + lg * 4 + r)) & 1) ? s[r] * 0.125f : -10000.0f;
    const float mv = fmaxf(fmaxf(vals[0], vals[1]), fmaxf(vals[2], vals[3]));
    const float mn = fmaxf(mrun, mv);
    float add = 0.f;
    #pragma unroll
    for (int r = 0; r < 4; ++r) add += __expf(vals[r] - mn);
    lrun = lrun * __expf(mrun - mn) + add;
    mrun = mn;
  }
  // merge the 4 lg-groups (lanes lr, lr+16, lr+32, lr+48)
  #pragma unroll
  for (int off = 16; off <= 32; off <<= 1) {
    const float om = __shfl_xor(mrun, off);
    const float ol = __shfl_xor(lrun, off);
    const float mn = fmaxf(mrun, om);
    lrun = lrun * __expf(mrun - mn) + ol * __expf(om - mn);
    mrun = mn;
  }
  if (lg == 0) {
    const size_t o = ((size_t)bh * SEQ + q0w + lr) * 8 + (size_t)kb * 2;
    stats_part[o] = mrun;
    stats_part[o + 1] = lrun;
  }
}

// ---------------------------------------------------------------------------
// Combine 4 k-block partials per row -> (m, 1/l)
// ---------------------------------------------------------------------------
__global__ __launch_bounds__(256) void stats_reduce_kernel(
    const float* __restrict__ part, float* __restrict__ fin) {
  const int idx = blockIdx.x * 256 + threadIdx.x;  // 32768 rows
  const float* p = part + (size_t)idx * 8;
  float m = p[0];
  #pragma unroll
  for (int i = 1; i < 4; ++i) m = fmaxf(m, p[i * 2]);
  float l = 0.f;
  #pragma unroll
  for (int i = 0; i < 4; ++i) l += p[i * 2 + 1] * __expf(p[i * 2] - m);
  fin[(size_t)idx * 2] = m;
  fin[(size_t)idx * 2 + 1] = 1.0f / l;
}

// ---------------------------------------------------------------------------
// K3 v3 (swapped): block = 8 waves = 4 q16-tiles x 2 k-halves; no main-loop
// LDS/barriers. Lane owns q-row lr: vectorized 16B p-store; p frag feeds
// v_mfma_f32_16x16x16_f16 PV directly (A[lr][lg*4+j] == p reg j). 2-way
// k-split reduced via 16KB LDS at the end.
// ---------------------------------------------------------------------------
__global__ __launch_bounds__(512) void pv_fused_kernel(
    const unsigned short* __restrict__ Qhi, const unsigned short* __restrict__ Qlo,
    const unsigned short* __restrict__ Khi, const unsigned short* __restrict__ Klo,
    const unsigned int* __restrict__ bits, const float* __restrict__ statsf,
    const unsigned short* __restrict__ Vt, float* __restrict__ attn,
    unsigned short* __restrict__ ctx16) {
  __shared__ f32x4 red[4][4][64];  // 16 KB
  const int bh = blockIdx.y, b = bh >> 3, h = bh & 7;
  const int tid = threadIdx.x, wv = tid >> 6, lane = tid & 63;
  const int lr = lane & 15, lg = lane >> 4;
  const int qi = wv & 3, ks = wv >> 2;
  const int q0w = blockIdx.x * 64 + qi * 16;

  FragU qh[2], ql[2];
  #pragma unroll
  for (int dc = 0; dc < 2; ++dc) {
    const size_t qidx = ((size_t)bh * SEQ + q0w + lr) * DK + dc * 32 + lg * 8;
    qh[dc].u = *(const uint4*)&Qhi[qidx];
    ql[dc].u = *(const uint4*)&Qlo[qidx];
  }
  const float2 st = *(const float2*)&statsf[((size_t)bh * SEQ + q0w + lr) * 2];
  const float mrow = st.x, ilrow = st.y;
  const unsigned int* brow = bits + ((size_t)b * SEQ + q0w + lr) * 64 + ks * 32;
  float* arow = attn + ((size_t)bh * SEQ + q0w + lr) * SEQ + ks * 1024;
  const size_t kbase0 = (size_t)bh * SEQ + ks * 1024;
  const size_t vbase = (size_t)bh * DK * SEQ + ks * 1024;

  f32x4 acc[4] = {};
  for (int kt = 0; kt < 64; ++kt) {
    FragU kh0, kh1, kl0, kl1;
    const size_t krow = (kbase0 + kt * 16 + lr) * DK + lg * 8;
    kh0.u = *(const uint4*)&Khi[krow];
    kh1.u = *(const uint4*)&Khi[krow + 32];
    kl0.u = *(const uint4*)&Klo[krow];
    kl1.u = *(const uint4*)&Klo[krow + 32];
    f32x4 s = s_tile(kh0, kl0, kh1, kl1, qh[0], ql[0], qh[1], ql[1]);

    const unsigned int w = brow[kt >> 1];
    const int bsh = (kt & 1) << 4;
    f32x4 p;
    F16U pa;
    #pragma unroll
    for (int r = 0; r < 4; ++r) {
      const float sv = ((w >> (bsh + lg * 4 + r)) & 1) ? s[r] * 0.125f : -10000.0f;
      p[r] = __expf(sv - mrow) * ilrow;
      pa.e[r] = (_Float16)p[r];
    }
    *(f32x4*)&arow[kt * 16 + lg * 4] = p;

    #pragma unroll
    for (int dt = 0; dt < 4; ++dt) {
      F16U vv;
      vv.u = *(const uint2*)&Vt[vbase + (size_t)(dt * 16 + lr) * SEQ + kt * 16 + lg * 4];
      acc[dt] = __builtin_amdgcn_mfma_f32_16x16x16f16(pa.h, vv.h, acc[dt], 0, 0, 0);
    }
  }

  if (ks == 1) {
    #pragma unroll
    for (int dt = 0; dt < 4; ++dt) red[qi][dt][lane] = acc[dt];
  }
  __syncthreads();
  if (ks == 0) {
    #pragma unroll
    for (int dt = 0; dt < 4; ++dt) {
      acc[dt] += red[qi][dt][lane];
      #pragma unroll
      for (int r = 0; r < 4; ++r) {
        const int q = q0w + lg * 4 + r;
        ctx16[((size_t)(b * SEQ + q)) * DMODEL + h * DK + dt * 16 + lr] =
            f32_to_bf16(acc[dt][r]);
      }
    }
  }
}

// ---------------------------------------------------------------------------
extern "C" void kernel_launch(void* const* d_in, const int* in_sizes, int n_in,
                              void* d_out, int out_size, void* d_ws,
                              size_t ws_size, hipStream_t stream) {
  const float* q = (const float*)d_in[0];
  const float* k = (const float*)d_in[1];
  const float* v = (const float*)d_in[2];
  const int* mask = (const int*)d_in[3];
  const float* Wq = (const float*)d_in[4];
  const float* bq = (const float*)d_in[5];
  const float* Wk = (const float*)d_in[6];
  const float* bk = (const float*)d_in[7];
  const float* Wv = (const float*)d_in[8];
  const float* bv = (const float*)d_in[9];
  const float* Wo = (const float*)d_in[10];
  const float* bo = (const float*)d_in[11];

  float* out = (float*)d_out;
  float* attn = out + (size_t)BATCH * SEQ * DMODEL;

  char* w = (char*)d_ws;
  const size_t MB = 1u << 20;
  unsigned short* Qhi = (unsigned short*)(w + 0 * MB);
  unsigned short* Qlo = (unsigned short*)(w + 4 * MB);
  unsigned short* Khi = (unsigned short*)(w + 8 * MB);
  unsigned short* Klo = (unsigned short*)(w + 12 * MB);
  unsigned short* Vh16 = (unsigned short*)(w + 16 * MB);   // f16; dead after vtrans
  unsigned short* Vt = (unsigned short*)(w + 20 * MB);     // f16 [bh][d][s]
  unsigned int* bits = (unsigned int*)(w + 24 * MB);       // 1 MB
  float* stats_part = (float*)(w + 25 * MB);               // 1 MB
  float* statsf = (float*)(w + 26 * MB);                   // 256 KB
  unsigned short* WtHi = (unsigned short*)(w + 26 * MB + 256 * 1024);  // 512 KB
  unsigned short* WtLo = (unsigned short*)(w + 26 * MB + 768 * 1024);  // 512 KB
  unsigned short* ctx16 = (unsigned short*)(w + 16 * MB);  // overlays Vh16

  dim3 blk(256);
  pack_mask_kernel<<<dim3(BATCH * SEQ), blk, 0, stream>>>(mask, bits);

  wsplit_kernel<<<dim3(8, 8), blk, 0, stream>>>(Wq, WtHi, WtLo);
  proj_mfma_kernel<1><<<dim3(64, 16), blk, 0, stream>>>(q, nullptr, WtHi, WtLo, bq,
                                                        nullptr, Qhi, Qlo);
  wsplit_kernel<<<dim3(8, 8), blk, 0, stream>>>(Wk, WtHi, WtLo);
  proj_mfma_kernel<1><<<dim3(64, 16), blk, 0, stream>>>(k, nullptr, WtHi, WtLo, bk,
                                                        nullptr, Khi, Klo);
  wsplit_kernel<<<dim3(8, 8), blk, 0, stream>>>(Wv, WtHi, WtLo);
  proj_mfma_kernel<2><<<dim3(64, 16), blk, 0, stream>>>(v, nullptr, WtHi, WtLo, bv,
                                                        nullptr, Vh16, nullptr);
  vtrans_kernel<<<dim3(32, BH), blk, 0, stream>>>(Vh16, Vt);

  stats_kernel<<<dim3(32, 4, BH), blk, 0, stream>>>(Qhi, Qlo, Khi, Klo, bits, stats_part);
  stats_reduce_kernel<<<dim3(128), blk, 0, stream>>>(stats_part, statsf);
  pv_fused_kernel<<<dim3(32, BH), dim3(512), 0, stream>>>(Qhi, Qlo, Khi, Klo, bits,
                                                          statsf, Vt, attn, ctx16);

  wsplit_kernel<<<dim3(8, 8), blk, 0, stream>>>(Wo, WtHi, WtLo);
  proj_mfma_kernel<3><<<dim3(64, 16), blk, 0, stream>>>(nullptr, ctx16, WtHi, WtLo, bo,
                                                        out, nullptr, nullptr);
}

// Round 8
// 332.515 us; speedup vs baseline: 1.8499x; 1.8499x over previous
//
#include <hip/hip_runtime.h>
#include <math.h>

#define HEADS 8
#define DK 64
#define DMODEL 512
#define BATCH 2
#define SEQ 2048
#define BH (BATCH * HEADS)

using f32x4 = __attribute__((ext_vector_type(4))) float;
using s16x8 = __attribute__((ext_vector_type(8))) short;

union FragU {
  uint4 u;
  s16x8 s;
  unsigned short us[8];
};

__device__ __forceinline__ unsigned short f32_to_bf16(float f) {
  unsigned int u = __float_as_uint(f);
  u += 0x7fffu + ((u >> 16) & 1u);
  return (unsigned short)(u >> 16);
}
__device__ __forceinline__ float bf16_to_f32(unsigned short h) {
  return __uint_as_float(((unsigned int)h) << 16);
}

// ---------------------------------------------------------------------------
// mask int32 [B][S][S] -> packed bits [B][S][S/32]. One block per row.
// ---------------------------------------------------------------------------
__global__ __launch_bounds__(256) void pack_mask_kernel(
    const int* __restrict__ mask, unsigned int* __restrict__ bits) {
  const size_t row = blockIdx.x;  // B*S = 4096 rows
  const int wv = threadIdx.x >> 6, lane = threadIdx.x & 63;
  #pragma unroll
  for (int i = 0; i < 8; ++i) {
    const int c = wv * 512 + i * 64 + lane;
    unsigned long long bal = __ballot(mask[row * SEQ + c] != 0);
    if (lane == 0) {
      bits[row * 64 + (c >> 5)] = (unsigned int)bal;
      bits[row * 64 + (c >> 5) + 1] = (unsigned int)(bal >> 32);
    }
  }
}

// ---------------------------------------------------------------------------
// W[512][512] f32 -> Wt hi/lo bf16 in [n][k] (transposed) layout.
// ---------------------------------------------------------------------------
__global__ __launch_bounds__(256) void wsplit_kernel(
    const float* __restrict__ W, unsigned short* __restrict__ WtHi,
    unsigned short* __restrict__ WtLo) {
  __shared__ float t[64][65];
  const int k0 = blockIdx.x * 64, n0 = blockIdx.y * 64;
  const int tid = threadIdx.x;
  const int r = tid >> 2, c = (tid & 3) * 16;
  #pragma unroll
  for (int e = 0; e < 4; ++e) {
    f32x4 v = *(const f32x4*)&W[(size_t)(k0 + r) * DMODEL + n0 + c + e * 4];
    #pragma unroll
    for (int j = 0; j < 4; ++j) t[r][c + e * 4 + j] = v[j];
  }
  __syncthreads();
  const int rn = tid >> 2, ck = (tid & 3) * 16;
  #pragma unroll
  for (int half = 0; half < 2; ++half) {
    FragU hi, lo;
    #pragma unroll
    for (int e = 0; e < 8; ++e) {
      float x = t[ck + half * 8 + e][rn];
      unsigned short h = f32_to_bf16(x);
      hi.us[e] = h;
      lo.us[e] = f32_to_bf16(x - bf16_to_f32(h));
    }
    const size_t o = (size_t)(n0 + rn) * DMODEL + k0 + ck + half * 8;
    *(uint4*)&WtHi[o] = hi.u;
    *(uint4*)&WtLo[o] = lo.u;
  }
}

// ---------------------------------------------------------------------------
// MFMA projection GEMM v2: Y(4096x512) = X @ W + bias, Wt[n][k] hi/lo bf16.
// B-tile LDS-staged (shared by 4 waves); output via LDS transpose -> 128B-line
// coalesced uint4 stores. All Y layouts FLAT [4096][512].
// MODE 1: Y -> bf16 hi/lo pair; MODE 2: Y -> bf16; MODE 3: X bf16, Y f32.
// MFMA maps (verified): A[lr][lg*8+j]; B[lg*8+j][lr]; D[lg*4+r][lr].
// ---------------------------------------------------------------------------
template <int MODE>
__global__ __launch_bounds__(256) void proj_mfma_kernel(
    const float* __restrict__ X, const unsigned short* __restrict__ X16,
    const unsigned short* __restrict__ WtHi,
    const unsigned short* __restrict__ WtLo, const float* __restrict__ bias,
    float* __restrict__ Yf, unsigned short* __restrict__ Yhi,
    unsigned short* __restrict__ Ylo) {
  __shared__ unsigned short BsHi[64][72];
  __shared__ unsigned short BsLo[64][72];
  const int tid = threadIdx.x, wv = tid >> 6, lane = tid & 63;
  const int lr = lane & 15, lg = lane >> 4;
  const int m0 = blockIdx.x * 64;
  const int mw = m0 + wv * 16;
  const int n0 = blockIdx.y * 64;

  f32x4 acc[4] = {};
  for (int k0 = 0; k0 < 512; k0 += 64) {
    // A frags from global (before barriers so loads overlap)
    FragU ah[2], al[2];
    #pragma unroll
    for (int dc = 0; dc < 2; ++dc) {
      const size_t xi = (size_t)(mw + lr) * DMODEL + k0 + dc * 32 + lg * 8;
      if (MODE == 3) {
        ah[dc].u = *(const uint4*)&X16[xi];
      } else {
        f32x4 x0 = *(const f32x4*)&X[xi];
        f32x4 x1 = *(const f32x4*)&X[xi + 4];
        #pragma unroll
        for (int t = 0; t < 4; ++t) {
          unsigned short h0 = f32_to_bf16(x0[t]);
          unsigned short h1 = f32_to_bf16(x1[t]);
          ah[dc].us[t] = h0;
          ah[dc].us[4 + t] = h1;
          al[dc].us[t] = f32_to_bf16(x0[t] - bf16_to_f32(h0));
          al[dc].us[4 + t] = f32_to_bf16(x1[t] - bf16_to_f32(h1));
        }
      }
    }
    __syncthreads();  // previous iteration's B reads done
    #pragma unroll
    for (int e = 0; e < 2; ++e) {  // FULL 64x64 tile: 2 x 256 x uint4
      const int rr = (tid >> 3) + e * 32;
      const int cc = (tid & 7) * 8;
      *(uint4*)&BsHi[rr][cc] =
          *(const uint4*)&WtHi[(size_t)(n0 + rr) * DMODEL + k0 + cc];
      *(uint4*)&BsLo[rr][cc] =
          *(const uint4*)&WtLo[(size_t)(n0 + rr) * DMODEL + k0 + cc];
    }
    __syncthreads();
    #pragma unroll
    for (int jt = 0; jt < 4; ++jt) {
      #pragma unroll
      for (int dc = 0; dc < 2; ++dc) {
        FragU bh, bl;
        bh.u = *(const uint4*)&BsHi[jt * 16 + lr][dc * 32 + lg * 8];
        bl.u = *(const uint4*)&BsLo[jt * 16 + lr][dc * 32 + lg * 8];
        acc[jt] = __builtin_amdgcn_mfma_f32_16x16x32_bf16(ah[dc].s, bh.s, acc[jt], 0, 0, 0);
        acc[jt] = __builtin_amdgcn_mfma_f32_16x16x32_bf16(ah[dc].s, bl.s, acc[jt], 0, 0, 0);
        if (MODE != 3)
          acc[jt] = __builtin_amdgcn_mfma_f32_16x16x32_bf16(al[dc].s, bh.s, acc[jt], 0, 0, 0);
      }
    }
  }

  if (MODE == 3) {
    #pragma unroll
    for (int jt = 0; jt < 4; ++jt) {
      const int n = n0 + jt * 16 + lr;
      const float bi = bias[n];
      #pragma unroll
      for (int r = 0; r < 4; ++r)
        Yf[(size_t)(mw + lg * 4 + r) * DMODEL + n] = acc[jt][r] + bi;
    }
  } else {
    __syncthreads();  // last k0's B reads done, reuse Bs as output staging
    #pragma unroll
    for (int jt = 0; jt < 4; ++jt) {
      const int n = jt * 16 + lr;
      const float bi = bias[n0 + n];
      #pragma unroll
      for (int r = 0; r < 4; ++r) {
        const float v = acc[jt][r] + bi;
        const int row = wv * 16 + lg * 4 + r;
        unsigned short hi = f32_to_bf16(v);
        BsHi[row][n] = hi;
        if (MODE == 1) BsLo[row][n] = f32_to_bf16(v - bf16_to_f32(hi));
      }
    }
    __syncthreads();
    #pragma unroll
    for (int p = 0; p < 2; ++p) {
      const int row = (tid >> 3) + p * 32;
      const int ch = (tid & 7) * 8;
      const size_t o = (size_t)(m0 + row) * DMODEL + n0 + ch;
      *(uint4*)&Yhi[o] = *(uint4*)&BsHi[row][ch];
      if (MODE == 1) *(uint4*)&Ylo[o] = *(uint4*)&BsLo[row][ch];
    }
  }
}

// ---------------------------------------------------------------------------
// V flat [4096][512] bf16 -> Vt[bh][d][s] bf16
// ---------------------------------------------------------------------------
__global__ __launch_bounds__(256) void vtrans_kernel(
    const unsigned short* __restrict__ V16, unsigned short* __restrict__ Vt) {
  __shared__ unsigned short t[64][72];
  const int tid = threadIdx.x;
  const int bh = blockIdx.y, b = bh >> 3, h = bh & 7;
  const int s0 = blockIdx.x * 64;
  #pragma unroll
  for (int e = 0; e < 2; ++e) {
    int c = tid + e * 256;
    int r = c >> 3, c8 = (c & 7) * 8;
    *(uint4*)&t[r][c8] =
        *(const uint4*)&V16[(size_t)(b * SEQ + s0 + r) * DMODEL + h * DK + c8];
  }
  __syncthreads();
  const int d = tid >> 2, sc0 = (tid & 3) * 16;
  #pragma unroll
  for (int e = 0; e < 16; ++e)
    Vt[((size_t)bh * DK + d) * SEQ + s0 + sc0 + e] = t[sc0 + e][d];
}

// ---------------------------------------------------------------------------
// K1: split-bf16 QK^T stats (flat layout, XCD swizzle).
// Grid flat 2048: xcd=id&7 -> bh = xcd + 8*(slot&1)  (bh pinned per XCD).
// ---------------------------------------------------------------------------
__global__ __launch_bounds__(256) void stats_kernel(
    const unsigned short* __restrict__ Qhi, const unsigned short* __restrict__ Qlo,
    const unsigned short* __restrict__ Khi, const unsigned short* __restrict__ Klo,
    const unsigned int* __restrict__ bits, float* __restrict__ stats_part) {
  __shared__ float sm[4][64][2];
  const int id = blockIdx.x;
  const int xcd = id & 7, slot = id >> 3;
  const int bh = xcd + 8 * (slot & 1);
  const int r2 = slot >> 1;  // 0..127
  const int q0 = (r2 & 31) * 64;
  const int kb = r2 >> 5;  // 0..3
  const int b = bh >> 3, h = bh & 7;
  const int tid = threadIdx.x;
  const int wv = tid >> 6, lane = tid & 63;
  const int lr = lane & 15, lg = lane >> 4;

  FragU qh[4][2], ql[4][2];
  #pragma unroll
  for (int i = 0; i < 4; ++i)
    #pragma unroll
    for (int dc = 0; dc < 2; ++dc) {
      const size_t qi =
          (size_t)(b * SEQ + q0 + i * 16 + lr) * DMODEL + h * DK + dc * 32 + lg * 8;
      qh[i][dc].u = *(const uint4*)&Qhi[qi];
      ql[i][dc].u = *(const uint4*)&Qlo[qi];
    }

  const int kw0 = kb * 512 + wv * 128;
  float mf[4][4], lf[4][4];

  #pragma unroll
  for (int jg = 0; jg < 2; ++jg) {
    f32x4 s[4][4] = {};  // [jt4][i]
    #pragma unroll
    for (int jt4 = 0; jt4 < 4; ++jt4) {
      const int jt = jg * 4 + jt4;
      FragU kh[2], kl[2];
      #pragma unroll
      for (int dc = 0; dc < 2; ++dc) {
        const size_t kidx =
            (size_t)(b * SEQ + kw0 + jt * 16 + lr) * DMODEL + h * DK + dc * 32 + lg * 8;
        kh[dc].u = *(const uint4*)&Khi[kidx];
        kl[dc].u = *(const uint4*)&Klo[kidx];
      }
      #pragma unroll
      for (int i = 0; i < 4; ++i) {
        #pragma unroll
        for (int dc = 0; dc < 2; ++dc) {
          s[jt4][i] = __builtin_amdgcn_mfma_f32_16x16x32_bf16(qh[i][dc].s, kh[dc].s, s[jt4][i], 0, 0, 0);
          s[jt4][i] = __builtin_amdgcn_mfma_f32_16x16x32_bf16(qh[i][dc].s, kl[dc].s, s[jt4][i], 0, 0, 0);
          s[jt4][i] = __builtin_amdgcn_mfma_f32_16x16x32_bf16(ql[i][dc].s, kh[dc].s, s[jt4][i], 0, 0, 0);
        }
      }
    }
    #pragma unroll
    for (int i = 0; i < 4; ++i) {
      #pragma unroll
      for (int r = 0; r < 4; ++r) {
        const int q = q0 + i * 16 + lg * 4 + r;
        const size_t base = ((size_t)b * SEQ + q) * 64 + (kw0 >> 5);
        float vals[4];
        #pragma unroll
        for (int jt4 = 0; jt4 < 4; ++jt4) {
          const int jt = jg * 4 + jt4;
          const unsigned int w = bits[base + (jt >> 1)];
          const bool keep = (w >> (((jt & 1) << 4) + lr)) & 1;
          vals[jt4] = keep ? s[jt4][i][r] * 0.125f : -10000.0f;
        }
        float m = fmaxf(fmaxf(vals[0], vals[1]), fmaxf(vals[2], vals[3]));
        #pragma unroll
        for (int off = 1; off < 16; off <<= 1) m = fmaxf(m, __shfl_xor(m, off));
        float l = 0.f;
        #pragma unroll
        for (int jt4 = 0; jt4 < 4; ++jt4) l += __expf(vals[jt4] - m);
        #pragma unroll
        for (int off = 1; off < 16; off <<= 1) l += __shfl_xor(l, off);
        if (jg == 0) {
          mf[i][r] = m;
          lf[i][r] = l;
        } else {
          const float mn = fmaxf(mf[i][r], m);
          lf[i][r] = lf[i][r] * __expf(mf[i][r] - mn) + l * __expf(m - mn);
          mf[i][r] = mn;
        }
      }
    }
  }

  #pragma unroll
  for (int i = 0; i < 4; ++i)
    #pragma unroll
    for (int r = 0; r < 4; ++r)
      if (lr == 0) {
        sm[wv][i * 16 + lg * 4 + r][0] = mf[i][r];
        sm[wv][i * 16 + lg * 4 + r][1] = lf[i][r];
      }
  __syncthreads();
  if (tid < 64) {
    float m = sm[0][tid][0];
    #pragma unroll
    for (int w = 1; w < 4; ++w) m = fmaxf(m, sm[w][tid][0]);
    float l = 0.f;
    #pragma unroll
    for (int w = 0; w < 4; ++w) l += sm[w][tid][1] * __expf(sm[w][tid][0] - m);
    const size_t o = ((size_t)bh * SEQ + q0 + tid) * 8 + (size_t)kb * 2;
    stats_part[o] = m;
    stats_part[o + 1] = l;
  }
}

// ---------------------------------------------------------------------------
// Combine 4 k-block partials per row -> (m, 1/l)
// ---------------------------------------------------------------------------
__global__ __launch_bounds__(256) void stats_reduce_kernel(
    const float* __restrict__ part, float* __restrict__ fin) {
  const int idx = blockIdx.x * 256 + threadIdx.x;  // 32768 rows
  const float* p = part + (size_t)idx * 8;
  float m = p[0];
  #pragma unroll
  for (int i = 1; i < 4; ++i) m = fmaxf(m, p[i * 2]);
  float l = 0.f;
  #pragma unroll
  for (int i = 0; i < 4; ++i) l += p[i * 2 + 1] * __expf(p[i * 2] - m);
  fin[(size_t)idx * 2] = m;
  fin[(size_t)idx * 2 + 1] = 1.0f / l;
}

// ---------------------------------------------------------------------------
// K3 (pv v1 structure, flat layout, XCD swizzle, 4-wave/64-row blocks):
// recompute S (same MFMA order as stats), write final p once, PV MFMA.
// K staged in LDS per kt, shared by 4 waves; p routed through per-wave pbuf
// to convert D-layout -> A-frag layout.
// ---------------------------------------------------------------------------
__global__ __launch_bounds__(256) void pv_fused_kernel(
    const unsigned short* __restrict__ Qhi, const unsigned short* __restrict__ Qlo,
    const unsigned short* __restrict__ Khi, const unsigned short* __restrict__ Klo,
    const unsigned int* __restrict__ bits, const float* __restrict__ statsf,
    const unsigned short* __restrict__ Vt, float* __restrict__ attn,
    unsigned short* __restrict__ ctx16) {
  __shared__ unsigned short Kh_s[64 * 72];
  __shared__ unsigned short Kl_s[64 * 72];
  __shared__ unsigned short pbuf[4][16 * 72];
  const int id = blockIdx.x;
  const int xcd = id & 7, slot = id >> 3;  // slot 0..63
  const int bh = xcd + 8 * (slot & 1);
  const int qt = slot >> 1;  // 0..31
  const int b = bh >> 3, h = bh & 7;
  const int tid = threadIdx.x, wv = tid >> 6, lane = tid & 63;
  const int lr = lane & 15, lg = lane >> 4;
  const int qw = qt * 64 + wv * 16;

  FragU qh[2], ql[2];
  #pragma unroll
  for (int dc = 0; dc < 2; ++dc) {
    const size_t qi = (size_t)(b * SEQ + qw + lr) * DMODEL + h * DK + dc * 32 + lg * 8;
    qh[dc].u = *(const uint4*)&Qhi[qi];
    ql[dc].u = *(const uint4*)&Qlo[qi];
  }
  float mr[4], il[4];
  size_t wbase[4], abase[4];
  #pragma unroll
  for (int r = 0; r < 4; ++r) {
    const int q = qw + lg * 4 + r;
    mr[r] = statsf[((size_t)bh * SEQ + q) * 2];
    il[r] = statsf[((size_t)bh * SEQ + q) * 2 + 1];
    wbase[r] = ((size_t)b * SEQ + q) * 64;
    abase[r] = ((size_t)bh * SEQ + q) * SEQ;
  }
  unsigned short* pb = pbuf[wv];
  f32x4 acc[4] = {};

  for (int kt = 0; kt < 32; ++kt) {
    const int kbase = kt * 64;
    __syncthreads();
    #pragma unroll
    for (int e = 0; e < 2; ++e) {  // FULL 64x64 tile: 2 x 256 x uint4
      const int rr = (tid >> 3) + e * 32;
      const int cc = (tid & 7) * 8;
      const size_t gi = (size_t)(b * SEQ + kbase + rr) * DMODEL + h * DK + cc;
      *(uint4*)&Kh_s[rr * 72 + cc] = *(const uint4*)&Khi[gi];
      *(uint4*)&Kl_s[rr * 72 + cc] = *(const uint4*)&Klo[gi];
    }
    __syncthreads();
    #pragma unroll
    for (int jt = 0; jt < 4; ++jt) {
      f32x4 sa = {};
      #pragma unroll
      for (int dc = 0; dc < 2; ++dc) {
        FragU kh, kl;
        const int ko = (jt * 16 + lr) * 72 + dc * 32 + lg * 8;
        kh.u = *(const uint4*)&Kh_s[ko];
        kl.u = *(const uint4*)&Kl_s[ko];
        sa = __builtin_amdgcn_mfma_f32_16x16x32_bf16(qh[dc].s, kh.s, sa, 0, 0, 0);
        sa = __builtin_amdgcn_mfma_f32_16x16x32_bf16(qh[dc].s, kl.s, sa, 0, 0, 0);
        sa = __builtin_amdgcn_mfma_f32_16x16x32_bf16(ql[dc].s, kh.s, sa, 0, 0, 0);
      }
      #pragma unroll
      for (int r = 0; r < 4; ++r) {
        const unsigned int w = bits[wbase[r] + kt * 2 + (jt >> 1)];
        const bool keep = (w >> (((jt & 1) << 4) + lr)) & 1;
        const float sv = keep ? sa[r] * 0.125f : -10000.0f;
        const float p = __expf(sv - mr[r]) * il[r];
        attn[abase[r] + kbase + jt * 16 + lr] = p;
        pb[(lg * 4 + r) * 72 + jt * 16 + lr] = f32_to_bf16(p);
      }
    }
    #pragma unroll
    for (int dc2 = 0; dc2 < 2; ++dc2) {
      FragU pa;
      pa.u = *(const uint4*)&pb[lr * 72 + dc2 * 32 + lg * 8];
      #pragma unroll
      for (int dt = 0; dt < 4; ++dt) {
        FragU bv;
        bv.u = *(const uint4*)&Vt[((size_t)bh * DK + dt * 16 + lr) * SEQ + kbase +
                                  dc2 * 32 + lg * 8];
        acc[dt] = __builtin_amdgcn_mfma_f32_16x16x32_bf16(pa.s, bv.s, acc[dt], 0, 0, 0);
      }
    }
  }
  #pragma unroll
  for (int dt = 0; dt < 4; ++dt)
    #pragma unroll
    for (int r = 0; r < 4; ++r) {
      const int q = qw + lg * 4 + r;
      ctx16[(size_t)(b * SEQ + q) * DMODEL + h * DK + dt * 16 + lr] =
          f32_to_bf16(acc[dt][r]);
    }
}

// ---------------------------------------------------------------------------
extern "C" void kernel_launch(void* const* d_in, const int* in_sizes, int n_in,
                              void* d_out, int out_size, void* d_ws,
                              size_t ws_size, hipStream_t stream) {
  const float* q = (const float*)d_in[0];
  const float* k = (const float*)d_in[1];
  const float* v = (const float*)d_in[2];
  const int* mask = (const int*)d_in[3];
  const float* Wq = (const float*)d_in[4];
  const float* bq = (const float*)d_in[5];
  const float* Wk = (const float*)d_in[6];
  const float* bk = (const float*)d_in[7];
  const float* Wv = (const float*)d_in[8];
  const float* bv = (const float*)d_in[9];
  const float* Wo = (const float*)d_in[10];
  const float* bo = (const float*)d_in[11];

  float* out = (float*)d_out;
  float* attn = out + (size_t)BATCH * SEQ * DMODEL;

  char* w = (char*)d_ws;
  const size_t MB = 1u << 20;
  unsigned short* Qhi = (unsigned short*)(w + 0 * MB);     // flat [4096][512]
  unsigned short* Qlo = (unsigned short*)(w + 4 * MB);
  unsigned short* Khi = (unsigned short*)(w + 8 * MB);
  unsigned short* Klo = (unsigned short*)(w + 12 * MB);
  unsigned short* V16 = (unsigned short*)(w + 16 * MB);    // dead after vtrans
  unsigned short* Vt = (unsigned short*)(w + 20 * MB);     // [bh][d][s]
  unsigned int* bits = (unsigned int*)(w + 24 * MB);       // 1 MB
  float* stats_part = (float*)(w + 25 * MB);               // 1 MB
  float* statsf = (float*)(w + 26 * MB);                   // 256 KB
  unsigned short* WtHi = (unsigned short*)(w + 26 * MB + 256 * 1024);  // 512 KB
  unsigned short* WtLo = (unsigned short*)(w + 26 * MB + 768 * 1024);  // 512 KB
  unsigned short* ctx16 = (unsigned short*)(w + 16 * MB);  // overlays V16

  dim3 blk(256);
  pack_mask_kernel<<<dim3(BATCH * SEQ), blk, 0, stream>>>(mask, bits);

  wsplit_kernel<<<dim3(8, 8), blk, 0, stream>>>(Wq, WtHi, WtLo);
  proj_mfma_kernel<1><<<dim3(64, 8), blk, 0, stream>>>(q, nullptr, WtHi, WtLo, bq,
                                                       nullptr, Qhi, Qlo);
  wsplit_kernel<<<dim3(8, 8), blk, 0, stream>>>(Wk, WtHi, WtLo);
  proj_mfma_kernel<1><<<dim3(64, 8), blk, 0, stream>>>(k, nullptr, WtHi, WtLo, bk,
                                                       nullptr, Khi, Klo);
  wsplit_kernel<<<dim3(8, 8), blk, 0, stream>>>(Wv, WtHi, WtLo);
  proj_mfma_kernel<2><<<dim3(64, 8), blk, 0, stream>>>(v, nullptr, WtHi, WtLo, bv,
                                                       nullptr, V16, nullptr);
  vtrans_kernel<<<dim3(32, BH), blk, 0, stream>>>(V16, Vt);

  stats_kernel<<<dim3(2048), blk, 0, stream>>>(Qhi, Qlo, Khi, Klo, bits, stats_part);
  stats_reduce_kernel<<<dim3(128), blk, 0, stream>>>(stats_part, statsf);
  pv_fused_kernel<<<dim3(512), blk, 0, stream>>>(Qhi, Qlo, Khi, Klo, bits,
                                                 statsf, Vt, attn, ctx16);

  wsplit_kernel<<<dim3(8, 8), blk, 0, stream>>>(Wo, WtHi, WtLo);
  proj_mfma_kernel<3><<<dim3(64, 8), blk, 0, stream>>>(nullptr, ctx16, WtHi, WtLo, bo,
                                                       out, nullptr, nullptr);
}